// Round 1
// baseline (21807.071 us; speedup 1.0000x reference)
//
#include <hip/hip_runtime.h>
#include <hip/hip_cooperative_groups.h>
#include <math.h>

namespace cg = cooperative_groups;

// Problem dims
#define B_  128
#define T_  512
#define I_  256
#define H_  512
#define O_  256
#define NP  2048            // 4*H (gate-interleaved n' = h*4+g)
#define BT  65536           // B*T
#define HB  65536           // H*B

// ---------------------------------------------------------------------------
// Prep: build transposed/gathered weight layouts + fused bias vectors.
//  Wt  [K=512][NP]   : Wt[k][h*4+g]   = Wh_g[h][k]      (recurrent, transposed+interleaved)
//  WgT [I][NP]       : WgT[i][h*4+g]  = Wx_g[h][i]      (x-weights, transposed+interleaved)
//  WphT[H][O]        : WphT[h][o]     = Wph[o][h]
//  xb  [NP]          : Wx_b_g[h] + b_g[h]
//  hb  [NP]          : Wh_b_g[h]
//  pb  [O]           : Wph_b[o] + bp[o]
// ---------------------------------------------------------------------------
struct PrepArgs {
    const float* Whw[4];
    const float* Wxw[4];
    const float* Wxb[4];
    const float* Whb[4];
    const float* bg[4];
    const float* Wph_w;
    const float* Wph_b;
    const float* bp;
    float* Wt; float* WgT; float* WphT;
    float* xb; float* hb; float* pb;
};

#define PREP_TOTAL (1048576 + 524288 + 131072 + 2048 + 2048 + 256)

__global__ __launch_bounds__(256) void k_prep(PrepArgs a) {
    int idx = blockIdx.x * 256 + threadIdx.x;
    if (idx >= PREP_TOTAL) return;
    int q = idx;
    if (q < 1048576) {                       // Wt [512][2048]
        int k = q >> 11, n = q & 2047;
        int g = n & 3, h = n >> 2;
        a.Wt[q] = a.Whw[g][h * H_ + k];
        return;
    }
    q -= 1048576;
    if (q < 524288) {                        // WgT [256][2048]
        int i = q >> 11, n = q & 2047;
        int g = n & 3, h = n >> 2;
        a.WgT[q] = a.Wxw[g][h * I_ + i];
        return;
    }
    q -= 524288;
    if (q < 131072) {                        // WphT [512][256]
        int h = q >> 8, o = q & 255;
        a.WphT[q] = a.Wph_w[o * H_ + h];
        return;
    }
    q -= 131072;
    if (q < 2048) {                          // xb
        int g = q & 3, h = q >> 2;
        a.xb[q] = a.Wxb[g][h] + a.bg[g][h];
        return;
    }
    q -= 2048;
    if (q < 2048) {                          // hb
        int g = q & 3, h = q >> 2;
        a.hb[q] = a.Whb[g][h];
        return;
    }
    q -= 2048;
    a.pb[q] = a.Wph_b[q] + a.bp[q];          // pb
}

// ---------------------------------------------------------------------------
// Transpose x: xT2[i][t*128+b] = x[b][t][i]
// 32x32 LDS tile transpose, grid (BT/32, I/32), 256 threads (32x8).
// ---------------------------------------------------------------------------
__global__ __launch_bounds__(256) void k_transpose(const float* __restrict__ x,
                                                   float* __restrict__ xT2) {
    __shared__ float lds[32][33];
    int tid = threadIdx.x;
    int tx = tid & 31, ty = tid >> 5;       // 32 x 8
    int j0 = blockIdx.x * 32;               // j = t*128 + b; tile within one t (32|128)
    int i0 = blockIdx.y * 32;
    int t  = j0 >> 7;
    int b0 = j0 & 127;
#pragma unroll
    for (int rr = 0; rr < 4; ++rr) {
        int jj = ty + rr * 8;               // b offset
        lds[jj][tx] = x[((size_t)(b0 + jj) * T_ + t) * I_ + i0 + tx];
    }
    __syncthreads();
#pragma unroll
    for (int rr = 0; rr < 4; ++rr) {
        int ii = ty + rr * 8;
        xT2[(size_t)(i0 + ii) * BT + j0 + tx] = lds[tx][ii];
    }
}

// ---------------------------------------------------------------------------
// Persistent cooperative scan kernel: the entire 512-step recurrence.
// Grid 256 = 128 n'-tiles (16 wide) x 2 b-halves. Block 256 = 4 waves (K split).
// Per block: Wt slice (512x16, 32KB) + WgT slice (256x16, 16KB) cached in LDS
// once; cell state c lives in registers of the epilogue thread for all steps.
// x-projection folded into each step (no xp buffer, no big GEMM).
// grid.sync() once per step publishes hist[t+1] device-wide.
// ---------------------------------------------------------------------------
__device__ inline float sigm(float v) { return 1.f / (1.f + expf(-v)); }

__global__ __launch_bounds__(256, 1) void k_scan(const float* __restrict__ Wt,   // [512][2048]
                                                 const float* __restrict__ WgT,  // [256][2048]
                                                 const float* __restrict__ xT2,  // [256][BT]
                                                 const float* __restrict__ xb,   // [2048]
                                                 const float* __restrict__ hb,   // [2048]
                                                 float* __restrict__ hist) {     // [513][512][128]
    __shared__ float Wl[512 * 16];           // 32 KB  recurrent-weight slice, k-major
    __shared__ float Xl[256 * 16];           // 16 KB  x-weight slice, i-major
    __shared__ float red[4][16][64];         // 16 KB  cross-wave K reduction
    cg::grid_group grid = cg::this_grid();

    int tid = threadIdx.x;
    int wave = tid >> 6, lane = tid & 63;
    int nt = blockIdx.x >> 1, bh = blockIdx.x & 1;
    int n0 = nt * 16, b0 = bh * 64;
    int b = b0 + lane;

    // ---- one-time: stage weight slices into LDS (float4, coalesced rows) ----
    for (int idx = tid; idx < 512 * 4; idx += 256) {
        int k = idx >> 2, j4 = (idx & 3) << 2;
        *(float4*)&Wl[k * 16 + j4] = *(const float4*)&Wt[(size_t)k * NP + n0 + j4];
    }
    for (int idx = tid; idx < 256 * 4; idx += 256) {
        int i = idx >> 2, j4 = (idx & 3) << 2;
        *(float4*)&Xl[i * 16 + j4] = *(const float4*)&WgT[(size_t)i * NP + n0 + j4];
    }

    // ---- epilogue thread identity: owns all 4 gates of one (h, b) forever ----
    int b_l = tid & 63, h_i = tid >> 6;
    int n_e = n0 + h_i * 4;
    int h_e = nt * 4 + h_i;
    int bb = b0 + b_l;
    float xb4[4], hb4[4];
#pragma unroll
    for (int g = 0; g < 4; ++g) { xb4[g] = xb[n_e + g]; hb4[g] = hb[n_e + g]; }
    float c_reg = 0.f;                       // cell state, register-resident

    __syncthreads();

    for (int t = 0; t < T_; ++t) {
        const float* hrow = hist + (size_t)t * HB;
        float acc[16];
#pragma unroll
        for (int j = 0; j < 16; ++j) acc[j] = 0.f;

        {   // recurrent part: K chunk of 128 per wave, weights from LDS
            int k0 = wave * 128;
            const float* hp = hrow + (size_t)k0 * B_ + b;
            const float* wl = &Wl[k0 * 16];
            float hv[8];
#pragma unroll
            for (int u = 0; u < 8; ++u) hv[u] = hp[u * B_];
            for (int kb = 0; kb < 128; kb += 8) {
                float hn[8];
                if (kb + 8 < 128) {
                    const float* hp2 = hp + (size_t)(kb + 8) * B_;
#pragma unroll
                    for (int u = 0; u < 8; ++u) hn[u] = hp2[u * B_];
                }
#pragma unroll
                for (int u = 0; u < 8; ++u) {
                    const float* w = wl + (kb + u) * 16;
                    float h0 = hv[u];
#pragma unroll
                    for (int j = 0; j < 4; ++j) {
                        float4 wv = *(const float4*)(w + j * 4);
                        acc[j * 4 + 0] += h0 * wv.x;
                        acc[j * 4 + 1] += h0 * wv.y;
                        acc[j * 4 + 2] += h0 * wv.z;
                        acc[j * 4 + 3] += h0 * wv.w;
                    }
                }
#pragma unroll
                for (int u = 0; u < 8; ++u) hv[u] = hn[u];
            }
        }
        {   // x-projection fold: I chunk of 64 per wave, weights from LDS
            int i0 = wave * 64;
            const float* xpp = xT2 + (size_t)i0 * BT + (size_t)t * B_ + b;
            float xv[8];
#pragma unroll
            for (int u = 0; u < 8; ++u) xv[u] = xpp[(size_t)u * BT];
            for (int ib = 0; ib < 64; ib += 8) {
                float xn[8];
                if (ib + 8 < 64) {
                    const float* xp2 = xpp + (size_t)(ib + 8) * BT;
#pragma unroll
                    for (int u = 0; u < 8; ++u) xn[u] = xp2[(size_t)u * BT];
                }
#pragma unroll
                for (int u = 0; u < 8; ++u) {
                    const float* w = &Xl[(i0 + ib + u) * 16];
                    float x0 = xv[u];
#pragma unroll
                    for (int j = 0; j < 4; ++j) {
                        float4 wv = *(const float4*)(w + j * 4);
                        acc[j * 4 + 0] += x0 * wv.x;
                        acc[j * 4 + 1] += x0 * wv.y;
                        acc[j * 4 + 2] += x0 * wv.z;
                        acc[j * 4 + 3] += x0 * wv.w;
                    }
                }
#pragma unroll
                for (int u = 0; u < 8; ++u) xv[u] = xn[u];
            }
        }
#pragma unroll
        for (int j = 0; j < 16; ++j) red[wave][j][lane] = acc[j];
        __syncthreads();

        // epilogue: thread -> (b_l, h_i), owns all 4 gates of (b, h)
        float pre[4];
#pragma unroll
        for (int g = 0; g < 4; ++g) {
            int j = h_i * 4 + g;
            pre[g] = red[0][j][b_l] + red[1][j][b_l] + red[2][j][b_l] + red[3][j][b_l]
                   + hb4[g] + xb4[g];
        }
        float iv = sigm(pre[0]);
        float fv = sigm(pre[1]);
        float gv = tanhf(pre[2]);
        float ov = sigm(pre[3]);
        float cn = gv * iv + c_reg * fv;
        c_reg = cn;
        hist[(size_t)(t + 1) * HB + h_e * B_ + bb] = tanhf(cn) * ov;

        grid.sync();                          // publish h_{t+1} device-wide
    }
}

// ---------------------------------------------------------------------------
// Output projection: pT[t][o][b] = sum_h hist[t+1][h][b]*WphT[h][o] + pb[o]
// Grid (32, 512): 16 o-tiles x 2 b-halves, per t. Block 256 = 4 waves (K split).
// ---------------------------------------------------------------------------
__global__ __launch_bounds__(256, 1) void k_outproj(const float* __restrict__ WphT, // [512][256]
                                                    const float* __restrict__ pb,   // [256]
                                                    const float* __restrict__ hist,
                                                    float* __restrict__ pT) {       // [512][256][128]
    __shared__ float red[4][16][64];
    int tid = threadIdx.x;
    int wave = tid >> 6, lane = tid & 63;
    int t = blockIdx.y;
    int ot = blockIdx.x >> 1, bh = blockIdx.x & 1;
    int o0 = ot * 16, b0 = bh * 64;
    int b = b0 + lane;

    const float* hrow = hist + (size_t)(t + 1) * HB;
    float acc[16];
#pragma unroll
    for (int j = 0; j < 16; ++j) acc[j] = 0.f;

    int k0 = wave * 128;
    const float* hp = hrow + (size_t)k0 * B_ + b;
    const float* wp = WphT + (size_t)k0 * O_ + o0;
    float hv[8];
#pragma unroll
    for (int u = 0; u < 8; ++u) hv[u] = hp[u * B_];
    for (int kb = 0; kb < 128; kb += 8) {
        float hn[8];
        if (kb + 8 < 128) {
            const float* hp2 = hp + (size_t)(kb + 8) * B_;
#pragma unroll
            for (int u = 0; u < 8; ++u) hn[u] = hp2[u * B_];
        }
#pragma unroll
        for (int u = 0; u < 8; ++u) {
            const float* w = wp + (size_t)(kb + u) * O_;
            float h0 = hv[u];
#pragma unroll
            for (int j = 0; j < 4; ++j) {
                float4 wv = *(const float4*)(w + j * 4);
                acc[j * 4 + 0] += h0 * wv.x;
                acc[j * 4 + 1] += h0 * wv.y;
                acc[j * 4 + 2] += h0 * wv.z;
                acc[j * 4 + 3] += h0 * wv.w;
            }
        }
#pragma unroll
        for (int u = 0; u < 8; ++u) hv[u] = hn[u];
    }
#pragma unroll
    for (int j = 0; j < 16; ++j) red[wave][j][lane] = acc[j];
    __syncthreads();

    int b_l = tid & 63, oi = tid >> 6;
    int bb = b0 + b_l;
#pragma unroll
    for (int g = 0; g < 4; ++g) {
        int j = oi * 4 + g;
        int o = o0 + j;
        float v = red[0][j][b_l] + red[1][j][b_l] + red[2][j][b_l] + red[3][j][b_l] + pb[o];
        pT[(size_t)t * (O_ * B_) + (size_t)o * B_ + bb] = v;
    }
}

// ---------------------------------------------------------------------------
// Softmax over O + layout change to d_out[b][t][o].
// Grid 2048 = 512 t x 4 b-quarters(32). Block 256 (= 32 b x 8 o-chunks).
// ---------------------------------------------------------------------------
__global__ __launch_bounds__(256, 1) void k_softmax(const float* __restrict__ pT,
                                                    float* __restrict__ out) {
    __shared__ float sm[32][257];
    __shared__ float rmax[32][8];
    __shared__ float rsum[32][8];
    int tid = threadIdx.x;
    int t = blockIdx.x >> 2, bq = blockIdx.x & 3;
    int b0 = bq * 32;
    const float* src = pT + (size_t)t * (O_ * B_);

#pragma unroll 4
    for (int it = 0; it < 32; ++it) {
        int idx = it * 256 + tid;           // 8192 = 256 o x 32 b
        int o = idx >> 5, b_l = idx & 31;
        sm[b_l][o] = src[(size_t)o * B_ + b0 + b_l];
    }
    __syncthreads();

    int b_l = tid >> 3, oc = tid & 7;       // 32 b x 8 chunks of 32 o
    float m = -3.4e38f;
#pragma unroll 4
    for (int oo = 0; oo < 32; ++oo) m = fmaxf(m, sm[b_l][oc * 32 + oo]);
    rmax[b_l][oc] = m;
    __syncthreads();
    float mm = rmax[b_l][0];
#pragma unroll
    for (int c = 1; c < 8; ++c) mm = fmaxf(mm, rmax[b_l][c]);

    float s = 0.f;
#pragma unroll 4
    for (int oo = 0; oo < 32; ++oo) s += expf(sm[b_l][oc * 32 + oo] - mm);
    rsum[b_l][oc] = s;
    __syncthreads();
    float st = 0.f;
#pragma unroll
    for (int c = 0; c < 8; ++c) st += rsum[b_l][c];
    float inv = 1.f / st;

    int bb = b0 + b_l;
    float* dst = out + ((size_t)bb * T_ + t) * O_ + oc * 32;
#pragma unroll 4
    for (int oo = 0; oo < 32; ++oo)
        dst[oo] = expf(sm[b_l][oc * 32 + oo] - mm) * inv;
}

// ---------------------------------------------------------------------------
extern "C" void kernel_launch(void* const* d_in, const int* in_sizes, int n_in,
                              void* d_out, int out_size, void* d_ws, size_t ws_size,
                              hipStream_t stream) {
    const float* x = (const float*)d_in[0];

    float* ws = (float*)d_ws;
    size_t off = 0;
    auto alloc = [&](size_t n) { float* p = ws + off; off += n; return p; };

    float* hist = alloc((size_t)513 * HB);      // h history (slot 0 = h_{-1} = 0)
    float* Wt   = alloc((size_t)512 * NP);
    float* WgT  = alloc((size_t)I_ * NP);
    float* WphT = alloc((size_t)H_ * O_);
    float* xb   = alloc(NP);
    float* hb   = alloc(NP);
    float* pb   = alloc(O_);
    float* xT2  = alloc((size_t)I_ * BT);       // reused as pT after the scan
    float* pT   = xT2;

    if (ws_size < off * sizeof(float)) return;  // cannot run — fail cleanly

    // zero h_{-1}
    hipMemsetAsync(hist, 0, HB * sizeof(float), stream);

    PrepArgs pa;
    for (int g = 0; g < 4; ++g) {
        pa.Wxw[g] = (const float*)d_in[1 + 5 * g];
        pa.Wxb[g] = (const float*)d_in[2 + 5 * g];
        pa.Whw[g] = (const float*)d_in[3 + 5 * g];
        pa.Whb[g] = (const float*)d_in[4 + 5 * g];
        pa.bg[g]  = (const float*)d_in[5 + 5 * g];
    }
    pa.Wph_w = (const float*)d_in[21];
    pa.Wph_b = (const float*)d_in[22];
    pa.bp    = (const float*)d_in[23];
    pa.Wt = Wt; pa.WgT = WgT; pa.WphT = WphT;
    pa.xb = xb; pa.hb = hb; pa.pb = pb;

    k_prep<<<(PREP_TOTAL + 255) / 256, 256, 0, stream>>>(pa);
    k_transpose<<<dim3(BT / 32, I_ / 32), 256, 0, stream>>>(x, xT2);

    // the whole recurrence: one cooperative persistent kernel
    {
        void* args[] = {(void*)&Wt, (void*)&WgT, (void*)&xT2,
                        (void*)&xb, (void*)&hb, (void*)&hist};
        hipLaunchCooperativeKernel((const void*)k_scan, dim3(256), dim3(256),
                                   args, 0, stream);
    }

    k_outproj<<<dim3(32, T_), 256, 0, stream>>>(WphT, pb, hist, pT);
    k_softmax<<<T_ * 4, 256, 0, stream>>>(pT, (float*)d_out);
}

// Round 5
// 14722.159 us; speedup vs baseline: 1.4812x; 1.4812x over previous
//
#include <hip/hip_runtime.h>
#include <math.h>

// Problem dims
#define B_  128
#define T_  512
#define I_  256
#define H_  512
#define O_  256
#define NP  2048            // 4*H (gate-interleaved n' = h*4+g)
#define BT  65536           // B*T
#define HB  65536           // H*B

// ---------------------------------------------------------------------------
// Prep: build transposed/gathered weight layouts + fused bias vectors.
//  Wt  [K=512][NP]   : Wt[k][h*4+g]   = Wh_g[h][k]      (recurrent, transposed+interleaved)
//  WgT [I][NP]       : WgT[i][h*4+g]  = Wx_g[h][i]      (x-weights, transposed+interleaved)
//  WphT[H][O]        : WphT[h][o]     = Wph[o][h]
//  xb  [NP]          : Wx_b_g[h] + b_g[h]
//  hb  [NP]          : Wh_b_g[h]
//  pb  [O]           : Wph_b[o] + bp[o]
// ---------------------------------------------------------------------------
struct PrepArgs {
    const float* Whw[4];
    const float* Wxw[4];
    const float* Wxb[4];
    const float* Whb[4];
    const float* bg[4];
    const float* Wph_w;
    const float* Wph_b;
    const float* bp;
    float* Wt; float* WgT; float* WphT;
    float* xb; float* hb; float* pb;
};

#define PREP_TOTAL (1048576 + 524288 + 131072 + 2048 + 2048 + 256)

__global__ __launch_bounds__(256) void k_prep(PrepArgs a) {
    int idx = blockIdx.x * 256 + threadIdx.x;
    if (idx >= PREP_TOTAL) return;
    int q = idx;
    if (q < 1048576) {                       // Wt [512][2048]
        int k = q >> 11, n = q & 2047;
        int g = n & 3, h = n >> 2;
        a.Wt[q] = a.Whw[g][h * H_ + k];
        return;
    }
    q -= 1048576;
    if (q < 524288) {                        // WgT [256][2048]
        int i = q >> 11, n = q & 2047;
        int g = n & 3, h = n >> 2;
        a.WgT[q] = a.Wxw[g][h * I_ + i];
        return;
    }
    q -= 524288;
    if (q < 131072) {                        // WphT [512][256]
        int h = q >> 8, o = q & 255;
        a.WphT[q] = a.Wph_w[o * H_ + h];
        return;
    }
    q -= 131072;
    if (q < 2048) {                          // xb
        int g = q & 3, h = q >> 2;
        a.xb[q] = a.Wxb[g][h] + a.bg[g][h];
        return;
    }
    q -= 2048;
    if (q < 2048) {                          // hb
        int g = q & 3, h = q >> 2;
        a.hb[q] = a.Whb[g][h];
        return;
    }
    q -= 2048;
    a.pb[q] = a.Wph_b[q] + a.bp[q];          // pb
}

// ---------------------------------------------------------------------------
// Transpose x: xT2[i][t*128+b] = x[b][t][i]
// ---------------------------------------------------------------------------
__global__ __launch_bounds__(256) void k_transpose(const float* __restrict__ x,
                                                   float* __restrict__ xT2) {
    __shared__ float lds[32][33];
    int tid = threadIdx.x;
    int tx = tid & 31, ty = tid >> 5;       // 32 x 8
    int j0 = blockIdx.x * 32;               // j = t*128 + b; tile within one t (32|128)
    int i0 = blockIdx.y * 32;
    int t  = j0 >> 7;
    int b0 = j0 & 127;
#pragma unroll
    for (int rr = 0; rr < 4; ++rr) {
        int jj = ty + rr * 8;               // b offset
        lds[jj][tx] = x[((size_t)(b0 + jj) * T_ + t) * I_ + i0 + tx];
    }
    __syncthreads();
#pragma unroll
    for (int rr = 0; rr < 4; ++rr) {
        int ii = ty + rr * 8;
        xT2[(size_t)(i0 + ii) * BT + j0 + tx] = lds[tx][ii];
    }
}

// ---------------------------------------------------------------------------
// Per-timestep recurrent kernel, v2: 8 waves/block (2 waves/SIMD TLP).
// Grid 256 = 128 n'-tiles (16 wide) x 2 b-halves. Block 512 = 8 waves.
// Waves K-split the recurrent sum (64 rows each) and I-split the x-fold
// (32 rows each); weights wave-uniform from L2 (round-0-verified pattern).
// Launch boundary is the cross-block barrier (round-0-verified mechanism).
// ---------------------------------------------------------------------------
__device__ inline float sigm(float v) { return 1.f / (1.f + expf(-v)); }

__global__ __launch_bounds__(512, 1) void k_step2(const float* __restrict__ Wt,   // [512][2048]
                                                  const float* __restrict__ WgT,  // [256][2048]
                                                  const float* __restrict__ xT2,  // [256][BT]
                                                  const float* __restrict__ xb,   // [2048]
                                                  const float* __restrict__ hb,   // [2048]
                                                  float* __restrict__ hist,       // [513][512][128]
                                                  float* __restrict__ cT,         // [512][128]
                                                  int t) {
    __shared__ float red[8][16][64];         // 32 KB cross-wave reduction
    int tid = threadIdx.x;
    int wave = tid >> 6, lane = tid & 63;
    int nt = blockIdx.x >> 1, bh = blockIdx.x & 1;
    int n0 = nt * 16, b0 = bh * 64;
    int b = b0 + lane;

    const float* hrow = hist + (size_t)t * HB;
    float acc[16];
#pragma unroll
    for (int j = 0; j < 16; ++j) acc[j] = 0.f;

    {   // recurrent part: K chunk of 64 per wave, weights from L2 (uniform)
        int k0 = wave * 64;
        const float* hp = hrow + (size_t)k0 * B_ + b;
        const float* wp = Wt + (size_t)k0 * NP + n0;
        float hv[8];
#pragma unroll
        for (int u = 0; u < 8; ++u) hv[u] = hp[u * B_];
        for (int kb = 0; kb < 64; kb += 8) {
            float hn[8];
            if (kb + 8 < 64) {
                const float* hp2 = hp + (size_t)(kb + 8) * B_;
#pragma unroll
                for (int u = 0; u < 8; ++u) hn[u] = hp2[u * B_];
            }
#pragma unroll
            for (int u = 0; u < 8; ++u) {
                const float* w = wp + (size_t)(kb + u) * NP;
                float h0 = hv[u];
#pragma unroll
                for (int j = 0; j < 4; ++j) {
                    float4 wv = *(const float4*)(w + j * 4);
                    acc[j * 4 + 0] += h0 * wv.x;
                    acc[j * 4 + 1] += h0 * wv.y;
                    acc[j * 4 + 2] += h0 * wv.z;
                    acc[j * 4 + 3] += h0 * wv.w;
                }
            }
#pragma unroll
            for (int u = 0; u < 8; ++u) hv[u] = hn[u];
        }
    }
    {   // x-projection fold: I chunk of 32 per wave (round-0-verified shape)
        int i0 = wave * 32;
        const float* xpp = xT2 + (size_t)i0 * BT + (size_t)t * B_ + b;
        const float* wp  = WgT + (size_t)i0 * NP + n0;
#pragma unroll 4
        for (int ii = 0; ii < 32; ++ii) {
            float xv = xpp[(size_t)ii * BT];
            const float* w = wp + (size_t)ii * NP;
#pragma unroll
            for (int j = 0; j < 4; ++j) {
                float4 wv = *(const float4*)(w + j * 4);
                acc[j * 4 + 0] += xv * wv.x;
                acc[j * 4 + 1] += xv * wv.y;
                acc[j * 4 + 2] += xv * wv.z;
                acc[j * 4 + 3] += xv * wv.w;
            }
        }
    }
#pragma unroll
    for (int j = 0; j < 16; ++j) red[wave][j][lane] = acc[j];
    __syncthreads();

    // epilogue: threads 0..255 -> (b_l, h_i), owns all 4 gates of (b, h)
    if (tid < 256) {
        int b_l = tid & 63, h_i = tid >> 6;
        int n = n0 + h_i * 4;
        int h = nt * 4 + h_i;
        int bb = b0 + b_l;
        float pre[4];
#pragma unroll
        for (int g = 0; g < 4; ++g) {
            int j = h_i * 4 + g;
            float s = red[0][j][b_l];
#pragma unroll
            for (int w = 1; w < 8; ++w) s += red[w][j][b_l];
            pre[g] = s + hb[n + g] + xb[n + g];
        }
        float iv = sigm(pre[0]);
        float fv = sigm(pre[1]);
        float gv = tanhf(pre[2]);
        float ov = sigm(pre[3]);
        float c  = cT[h * B_ + bb];
        float cn = gv * iv + c * fv;
        cT[h * B_ + bb] = cn;
        hist[(size_t)(t + 1) * HB + h * B_ + bb] = tanhf(cn) * ov;
    }
}

// ---------------------------------------------------------------------------
// Output projection: pT[t][o][b] = sum_h hist[t+1][h][b]*WphT[h][o] + pb[o]
// ---------------------------------------------------------------------------
__global__ __launch_bounds__(256, 1) void k_outproj(const float* __restrict__ WphT, // [512][256]
                                                    const float* __restrict__ pb,   // [256]
                                                    const float* __restrict__ hist,
                                                    float* __restrict__ pT) {       // [512][256][128]
    __shared__ float red[4][16][64];
    int tid = threadIdx.x;
    int wave = tid >> 6, lane = tid & 63;
    int t = blockIdx.y;
    int ot = blockIdx.x >> 1, bh = blockIdx.x & 1;
    int o0 = ot * 16, b0 = bh * 64;
    int b = b0 + lane;

    const float* hrow = hist + (size_t)(t + 1) * HB;
    float acc[16];
#pragma unroll
    for (int j = 0; j < 16; ++j) acc[j] = 0.f;

    int k0 = wave * 128;
    const float* hp = hrow + (size_t)k0 * B_ + b;
    const float* wp = WphT + (size_t)k0 * O_ + o0;
    float hv[8];
#pragma unroll
    for (int u = 0; u < 8; ++u) hv[u] = hp[u * B_];
    for (int kb = 0; kb < 128; kb += 8) {
        float hn[8];
        if (kb + 8 < 128) {
            const float* hp2 = hp + (size_t)(kb + 8) * B_;
#pragma unroll
            for (int u = 0; u < 8; ++u) hn[u] = hp2[u * B_];
        }
#pragma unroll
        for (int u = 0; u < 8; ++u) {
            const float* w = wp + (size_t)(kb + u) * O_;
            float h0 = hv[u];
#pragma unroll
            for (int j = 0; j < 4; ++j) {
                float4 wv = *(const float4*)(w + j * 4);
                acc[j * 4 + 0] += h0 * wv.x;
                acc[j * 4 + 1] += h0 * wv.y;
                acc[j * 4 + 2] += h0 * wv.z;
                acc[j * 4 + 3] += h0 * wv.w;
            }
        }
#pragma unroll
        for (int u = 0; u < 8; ++u) hv[u] = hn[u];
    }
#pragma unroll
    for (int j = 0; j < 16; ++j) red[wave][j][lane] = acc[j];
    __syncthreads();

    int b_l = tid & 63, oi = tid >> 6;
    int bb = b0 + b_l;
#pragma unroll
    for (int g = 0; g < 4; ++g) {
        int j = oi * 4 + g;
        int o = o0 + j;
        float v = red[0][j][b_l] + red[1][j][b_l] + red[2][j][b_l] + red[3][j][b_l] + pb[o];
        pT[(size_t)t * (O_ * B_) + (size_t)o * B_ + bb] = v;
    }
}

// ---------------------------------------------------------------------------
// Softmax over O + layout change to d_out[b][t][o].
// ---------------------------------------------------------------------------
__global__ __launch_bounds__(256, 1) void k_softmax(const float* __restrict__ pT,
                                                    float* __restrict__ out) {
    __shared__ float sm[32][257];
    __shared__ float rmax[32][8];
    __shared__ float rsum[32][8];
    int tid = threadIdx.x;
    int t = blockIdx.x >> 2, bq = blockIdx.x & 3;
    int b0 = bq * 32;
    const float* src = pT + (size_t)t * (O_ * B_);

#pragma unroll 4
    for (int it = 0; it < 32; ++it) {
        int idx = it * 256 + tid;           // 8192 = 256 o x 32 b
        int o = idx >> 5, b_l = idx & 31;
        sm[b_l][o] = src[(size_t)o * B_ + b0 + b_l];
    }
    __syncthreads();

    int b_l = tid >> 3, oc = tid & 7;       // 32 b x 8 chunks of 32 o
    float m = -3.4e38f;
#pragma unroll 4
    for (int oo = 0; oo < 32; ++oo) m = fmaxf(m, sm[b_l][oc * 32 + oo]);
    rmax[b_l][oc] = m;
    __syncthreads();
    float mm = rmax[b_l][0];
#pragma unroll
    for (int c = 1; c < 8; ++c) mm = fmaxf(mm, rmax[b_l][c]);

    float s = 0.f;
#pragma unroll 4
    for (int oo = 0; oo < 32; ++oo) s += expf(sm[b_l][oc * 32 + oo] - mm);
    rsum[b_l][oc] = s;
    __syncthreads();
    float st = 0.f;
#pragma unroll
    for (int c = 0; c < 8; ++c) st += rsum[b_l][c];
    float inv = 1.f / st;

    int bb = b0 + b_l;
    float* dst = out + ((size_t)bb * T_ + t) * O_ + oc * 32;
#pragma unroll 4
    for (int oo = 0; oo < 32; ++oo)
        dst[oo] = expf(sm[b_l][oc * 32 + oo] - mm) * inv;
}

// ---------------------------------------------------------------------------
extern "C" void kernel_launch(void* const* d_in, const int* in_sizes, int n_in,
                              void* d_out, int out_size, void* d_ws, size_t ws_size,
                              hipStream_t stream) {
    const float* x = (const float*)d_in[0];

    float* ws = (float*)d_ws;
    size_t off = 0;
    auto alloc = [&](size_t n) { float* p = ws + off; off += n; return p; };

    float* hist = alloc((size_t)513 * HB);      // h history (slot 0 = h_{-1} = 0)
    float* cT   = alloc(HB);                    // cell state, transposed [h][b]
    float* Wt   = alloc((size_t)512 * NP);
    float* WgT  = alloc((size_t)I_ * NP);
    float* WphT = alloc((size_t)H_ * O_);
    float* xb   = alloc(NP);
    float* hb   = alloc(NP);
    float* pb   = alloc(O_);
    float* xT2  = alloc((size_t)I_ * BT);       // reused as pT after the scan
    float* pT   = xT2;

    if (ws_size < off * sizeof(float)) return;  // cannot run — fail cleanly

    // zero h_{-1} and c
    hipMemsetAsync(hist, 0, HB * sizeof(float), stream);
    hipMemsetAsync(cT, 0, HB * sizeof(float), stream);

    PrepArgs pa;
    for (int g = 0; g < 4; ++g) {
        pa.Wxw[g] = (const float*)d_in[1 + 5 * g];
        pa.Wxb[g] = (const float*)d_in[2 + 5 * g];
        pa.Whw[g] = (const float*)d_in[3 + 5 * g];
        pa.Whb[g] = (const float*)d_in[4 + 5 * g];
        pa.bg[g]  = (const float*)d_in[5 + 5 * g];
    }
    pa.Wph_w = (const float*)d_in[21];
    pa.Wph_b = (const float*)d_in[22];
    pa.bp    = (const float*)d_in[23];
    pa.Wt = Wt; pa.WgT = WgT; pa.WphT = WphT;
    pa.xb = xb; pa.hb = hb; pa.pb = pb;

    k_prep<<<(PREP_TOTAL + 255) / 256, 256, 0, stream>>>(pa);
    k_transpose<<<dim3(BT / 32, I_ / 32), 256, 0, stream>>>(x, xT2);

    // scan: launch boundary = cross-block barrier (verified mechanism)
    for (int t = 0; t < T_; ++t)
        k_step2<<<256, 512, 0, stream>>>(Wt, WgT, xT2, xb, hb, hist, cT, t);

    k_outproj<<<dim3(32, T_), 256, 0, stream>>>(WphT, pb, hist, pT);
    k_softmax<<<T_ * 4, 256, 0, stream>>>(pT, (float*)d_out);
}